// Round 12
// baseline (1844.283 us; speedup 1.0000x reference)
//
#include <hip/hip_runtime.h>

#define N_NODES 20000
#define N_EDGES 320000
#define CDIM    256
#define BE      1024
#define NBLK    313      // ceil(N_EDGES/BE)
#define NBN     20       // ceil(N_NODES/BE)
#define CH      8192     // serial-match chunk size
#define NGRP    (CH/64)  // 128 raw groups per chunk
#define NCH     ((N_EDGES + CH - 1) / CH)   // 40

#define OFF_X   0
#define OFF_EI  (N_NODES*CDIM)                 // 5120000
#define OFF_CL  (OFF_EI + 2*N_EDGES)           // 5760000
#define OFF_B   (OFF_CL + N_NODES)             // 5780000
#define OFF_NC  (OFF_B + N_NODES)              // 5800000

// ---------- XLA CPU tanh: rational approximation, plain mul/add f32 ----------
__device__ __forceinline__ float xla_tanh(float x) {
  float ax = fabsf(x);
  float xc = fminf(fmaxf(x, -9.0f), 9.0f);
  float x2 = __fmul_rn(xc, xc);
  float p = -2.76076847742355e-16f;
  p = __fadd_rn(__fmul_rn(p, x2), 2.00018790482477e-13f);
  p = __fadd_rn(__fmul_rn(p, x2), -8.60467152213735e-11f);
  p = __fadd_rn(__fmul_rn(p, x2), 5.12229709037114e-08f);
  p = __fadd_rn(__fmul_rn(p, x2), 1.48572235717979e-05f);
  p = __fadd_rn(__fmul_rn(p, x2), 6.37261928875436e-04f);
  p = __fadd_rn(__fmul_rn(p, x2), 4.89352455891786e-03f);
  float num = __fmul_rn(xc, p);
  float q = 1.19825839466702e-06f;
  q = __fadd_rn(__fmul_rn(q, x2), 1.18534705686654e-04f);
  q = __fadd_rn(__fmul_rn(q, x2), 2.26843463243900e-03f);
  q = __fadd_rn(__fmul_rn(q, x2), 4.89352518554385e-03f);
  float r = num / q;   // correctly-rounded f32 divide
  return (ax < 0.0004f) ? x : r;
}

// ---------- K0: per-node partial dots, sequential-k mul+add chain ----------
__global__ void k_node_dots(const float* __restrict__ x, const float* __restrict__ w,
                            float* __restrict__ p1, float* __restrict__ p2) {
  __shared__ float sw[2*CDIM];
  for (int i = threadIdx.x; i < 2*CDIM; i += blockDim.x) sw[i] = w[i];
  __syncthreads();
  int n = blockIdx.x * blockDim.x + threadIdx.x;
  if (n >= N_NODES) return;
  const float* row = x + (size_t)n * CDIM;
  float a1 = 0.f, a2 = 0.f;
  for (int k = 0; k < CDIM; ++k) {
    float xv = row[k];
    a1 = __fadd_rn(a1, __fmul_rn(xv, sw[k]));
    a2 = __fadd_rn(a2, __fmul_rn(xv, sw[CDIM + k]));
  }
  p1[n] = a1; p2[n] = a2;
}

// ---------- K1: edge scores + sort keys + FUSED pass-0 histogram ----------
// grid NBLK x 256; block b owns edges [b*BE, b*BE+BE)
__global__ void k_edge_scores_hist(const int* __restrict__ ei, const float* __restrict__ p1,
                                   const float* __restrict__ p2, const float* __restrict__ lb,
                                   float* __restrict__ e, unsigned* __restrict__ keyA,
                                   int* __restrict__ payA, unsigned* __restrict__ hist) {
  __shared__ unsigned h[256];
  int t = threadIdx.x;
  h[t] = 0;
  __syncthreads();
  int base = blockIdx.x * BE;
  for (int j = t; j < BE; j += 256) {
    int i = base + j;
    if (i >= N_EDGES) continue;
    int s = ei[i], d = ei[N_EDGES + i];
    float z = __fadd_rn(__fadd_rn(p1[s], p2[d]), lb[0]);
    float ev = __fadd_rn(xla_tanh(z), 0.5f);
    e[i] = ev;
    unsigned u = __float_as_uint(ev);
    u = (u >> 31) ? ~u : (u | 0x80000000u);   // ascending-order bits of e
    unsigned key = ~u;                         // ascending key == descending e
    keyA[i] = key;
    payA[i] = i;
    atomicAdd(&h[key & 255u], 1u);
  }
  __syncthreads();
  hist[t * NBLK + blockIdx.x] = h[t];
}

// ---------- radix sort (stable LSD, 4x8 bits) ----------
__global__ void k_radix_hist(const unsigned* __restrict__ key, int n, int shift,
                             unsigned* __restrict__ hist) {
  __shared__ unsigned h[256];
  int t = threadIdx.x;
  h[t] = 0;
  __syncthreads();
  int base = blockIdx.x * BE;
  for (int j = t; j < BE; j += 256) {
    int idx = base + j;
    if (idx < n) atomicAdd(&h[(key[idx] >> shift) & 255u], 1u);
  }
  __syncthreads();
  hist[t * NBLK + blockIdx.x] = h[t];
}

__global__ void k_radix_scan(unsigned* __restrict__ hist) {
  __shared__ unsigned sums[256];
  int t = threadIdx.x;
  unsigned rs = 0;
  for (int b = 0; b < NBLK; ++b) rs += hist[t * NBLK + b];
  sums[t] = rs;
  __syncthreads();
  for (int off = 1; off < 256; off <<= 1) {
    unsigned u2 = (t >= off) ? sums[t - off] : 0u;
    __syncthreads();
    sums[t] += u2;
    __syncthreads();
  }
  unsigned run = sums[t] - rs;   // exclusive base for bin t
  for (int b = 0; b < NBLK; ++b) {
    unsigned tmp = hist[t * NBLK + b];
    hist[t * NBLK + b] = run;
    run += tmp;
  }
}

__global__ void k_radix_scatter(const unsigned* __restrict__ key, const int* __restrict__ pay,
                                int n, int shift, const unsigned* __restrict__ hist,
                                unsigned* __restrict__ keyo, int* __restrict__ payo) {
  __shared__ unsigned mask[256][8];
  __shared__ unsigned rbase[256];
  int t = threadIdx.x;
  rbase[t] = hist[t * NBLK + blockIdx.x];
  __syncthreads();
  int base = blockIdx.x * BE;
  for (int tile = 0; tile < BE / 256; ++tile) {
    for (int wq = 0; wq < 8; ++wq) mask[t][wq] = 0u;
    __syncthreads();
    int idx = base + tile * 256 + t;
    unsigned k = 0; int bin = 0; int valid = (idx < n);
    if (valid) {
      k = key[idx];
      bin = (k >> shift) & 255;
      atomicOr(&mask[bin][t >> 5], 1u << (t & 31));
    }
    __syncthreads();
    if (valid) {
      int w = t >> 5;
      unsigned r = 0;
      for (int w2 = 0; w2 < w; ++w2) r += __popc(mask[bin][w2]);
      r += __popc(mask[bin][w] & ((1u << (t & 31)) - 1u));
      unsigned pos = rbase[bin] + r;
      keyo[pos] = k;
      payo[pos] = pay[idx];
    }
    __syncthreads();
    unsigned c = 0;
    for (int wq = 0; wq < 8; ++wq) c += __popc(mask[t][wq]);
    rbase[t] += c;
    __syncthreads();
  }
}

// ---------- final scatter pass FUSED with endpoint gather / worklist build ----
// writes: payo[pos]=orig-id, ss/dd[pos]=endpoints, wl[pos]=packed, take[pos]=0
__global__ void k_radix_scatter_final(const unsigned* __restrict__ key, const int* __restrict__ pay,
                                      int n, int shift, const unsigned* __restrict__ hist,
                                      const int* __restrict__ ei, int* __restrict__ payo,
                                      int* __restrict__ ss, int* __restrict__ dd,
                                      unsigned long long* __restrict__ wl,
                                      unsigned char* __restrict__ take) {
  __shared__ unsigned mask[256][8];
  __shared__ unsigned rbase[256];
  int t = threadIdx.x;
  rbase[t] = hist[t * NBLK + blockIdx.x];
  __syncthreads();
  int base = blockIdx.x * BE;
  for (int tile = 0; tile < BE / 256; ++tile) {
    for (int wq = 0; wq < 8; ++wq) mask[t][wq] = 0u;
    __syncthreads();
    int idx = base + tile * 256 + t;
    unsigned k = 0; int bin = 0; int valid = (idx < n);
    if (valid) {
      k = key[idx];
      bin = (k >> shift) & 255;
      atomicOr(&mask[bin][t >> 5], 1u << (t & 31));
    }
    __syncthreads();
    if (valid) {
      int w = t >> 5;
      unsigned r = 0;
      for (int w2 = 0; w2 < w; ++w2) r += __popc(mask[bin][w2]);
      r += __popc(mask[bin][w] & ((1u << (t & 31)) - 1u));
      unsigned pos = rbase[bin] + r;
      int o = pay[idx];
      int s = ei[o];
      int d = ei[N_EDGES + o];
      payo[pos] = o;
      ss[pos] = s;
      dd[pos] = d;
      wl[pos] = ((unsigned long long)pos << 30) | ((unsigned long long)(unsigned)s << 15)
              | (unsigned long long)(unsigned)d;
      take[pos] = 0;
    }
    __syncthreads();
    unsigned c = 0;
    for (int wq = 0; wq < 8; ++wq) c += __popc(mask[t][wq]);
    rbase[t] += c;
    __syncthreads();
  }
}

// ---------- K16: persistent single-block EXACT sequential greedy matching ----------
// R8 structure (serial phases, chunk-contiguous compaction, LDS-broadcast kmask
// build). NEW WALK: group g+1's avail gathers are ISSUED before group g's take
// loop and consumed after it (take loop is register/SALU-only, so the loads
// stay pending) -- the gather reflects kills from groups < g; kills from g
// itself are applied by a short readlane fix loop over the taken lanes'
// endpoints. Aliveness == exact avail at group start -> take-set identical.
__global__ __launch_bounds__(1024) void k_match(const unsigned long long* __restrict__ wl,
                                                unsigned char* __restrict__ take,
                                                int* __restrict__ g_avail) {
  __shared__ unsigned char avail[N_NODES];          // 20000 B
  __shared__ unsigned long long comp[CH];           // 65536 B
  __shared__ unsigned long long kmask[CH];          // 65536 B
  __shared__ unsigned gcnt[NGRP];                   // 512 B
  __shared__ unsigned gbase[NGRP];                  // 512 B
  __shared__ int s_ncomp;
  int t = threadIdx.x;
  int lane = t & 63, wid = t >> 6;
  unsigned long long lmask_lt = (lane == 0) ? 0ull : (~0ull >> (64 - lane));
  for (int n = t; n < N_NODES; n += 1024) avail[n] = 1;
  __syncthreads();
  for (int c = 0; c < NCH; ++c) {
    int base = c * CH;
    // --- 1a) stage + alive-count (wave wid owns raw groups wid*8 .. wid*8+7)
    unsigned long long myv[8];
    unsigned char myal[8];
    for (int it = 0; it < 8; ++it) {
      int rg = wid * 8 + it;
      int i = base + rg * 64 + lane;
      unsigned long long v = (i < N_EDGES) ? wl[i] : 0ull;
      bool a = false;
      if (i < N_EDGES) {
        int d = (int)(v & 0x7FFFu);
        int s = (int)((v >> 15) & 0x7FFFu);
        a = avail[s] && avail[d];
      }
      myv[it] = v; myal[it] = a ? 1 : 0;
      unsigned long long bal = __ballot(a);
      if (lane == 0) gcnt[rg] = (unsigned)__popcll(bal);
    }
    __syncthreads();
    // --- 1b) exclusive scan of 128 raw-group counts (wave 0)
    if (wid == 0) {
      unsigned a0 = gcnt[lane], a1 = gcnt[64 + lane];
      unsigned s0 = a0;
      for (int o = 1; o < 64; o <<= 1) { unsigned u = __shfl_up(s0, o); if (lane >= o) s0 += u; }
      unsigned tot0 = __shfl(s0, 63);
      unsigned s1 = a1;
      for (int o = 1; o < 64; o <<= 1) { unsigned u = __shfl_up(s1, o); if (lane >= o) s1 += u; }
      gbase[lane] = s0 - a0;
      gbase[64 + lane] = tot0 + s1 - a1;
      if (lane == 63) s_ncomp = (int)(tot0 + s1);
    }
    __syncthreads();
    // --- 1c) order-preserving writeback of alive edges
    for (int it = 0; it < 8; ++it) {
      int rg = wid * 8 + it;
      unsigned long long bal = __ballot(myal[it] != 0);
      if (myal[it]) {
        unsigned r = (unsigned)__popcll(bal & lmask_lt);
        comp[gbase[rg] + r] = myv[it];
      }
    }
    __syncthreads();
    int ncomp = s_ncomp;
    // --- 2) kill-mask build (R8 version: uniform LDS broadcast inner loop)
    for (int g = wid; g * 64 < ncomp; g += 16) {
      int i = g * 64 + lane;
      unsigned long long v = (i < ncomp) ? comp[i] : 0ull;
      int d = (int)(v & 0x7FFFu);
      int s = (int)((v >> 15) & 0x7FFFu);
      unsigned long long km = 1ull << lane;   // self bit
      if (i < ncomp) {
        int glen = ncomp - g * 64; if (glen > 64) glen = 64;
        for (int j = lane + 1; j < glen; ++j) {
          unsigned long long vj = comp[g * 64 + j];   // broadcast read
          int dj = (int)(vj & 0x7FFFu);
          int sj = (int)((vj >> 15) & 0x7FFFu);
          if (sj == s || sj == d || dj == s || dj == d) km |= 1ull << j;
        }
      }
      kmask[i] = km;
    }
    __syncthreads();
    // --- 3) wave-0 exact serial walk, gathers hidden behind the take loop
    if (wid == 0) {
      int ncomp0 = s_ncomp;
      if (ncomp0 > 0) {
        int ng = (ncomp0 + 63) >> 6;
        unsigned long long vcur = comp[lane];
        unsigned long long kcur = kmask[lane];
        int sc = (int)((vcur >> 15) & 0x7FFFu);
        int dc = (int)(vcur & 0x7FFFu);
        int glen0 = ncomp0 < 64 ? ncomp0 : 64;
        bool ac = (lane < glen0) && avail[sc] && avail[dc];
        for (int g = 0; g < ng; ++g) {
          // prefetch next group's data + ISSUE its avail gathers
          int glen_n = ncomp0 - (g + 1) * 64; if (glen_n > 64) glen_n = 64;
          int pi = ((g + 1) * 64 + lane) & (CH - 1);
          unsigned long long vnx = comp[pi];
          unsigned long long knx = kmask[pi];
          int sn = (int)((vnx >> 15) & 0x7FFFu);
          int dn = (int)(vnx & 0x7FFFu);
          unsigned char a1 = avail[sn];   // pending until after the take loop
          unsigned char a2 = avail[dn];
          // take loop on current group (register/SALU only -> loads stay pending)
          unsigned long long am = __ballot(ac);
          unsigned km_lo = (unsigned)kcur, km_hi = (unsigned)(kcur >> 32);
          unsigned long long tk = 0;
          while (am) {
            int j = __ffsll((long long)am) - 1;
            tk |= 1ull << j;
            unsigned long long kj =
                ((unsigned long long)(unsigned)__builtin_amdgcn_readlane((int)km_hi, j) << 32)
              | (unsigned long long)(unsigned)__builtin_amdgcn_readlane((int)km_lo, j);
            am &= ~kj;   // kills j itself + later same-endpoint edges in group
          }
          if ((tk >> lane) & 1ull) {
            take[(unsigned)(vcur >> 30)] = 1;
            avail[sc] = 0; avail[dc] = 0;
          }
          // fix next group's aliveness with THIS group's kills
          bool an = (glen_n > 0) && (lane < glen_n) && a1 && a2;
          unsigned long long tkit = tk;
          while (tkit) {
            int j = __ffsll((long long)tkit) - 1;
            tkit &= tkit - 1;
            int sj = __builtin_amdgcn_readlane(sc, j);
            int dj = __builtin_amdgcn_readlane(dc, j);
            an = an && !(sn == sj || sn == dj || dn == sj || dn == dj);
          }
          vcur = vnx; kcur = knx; sc = sn; dc = dn; ac = an;
        }
      }
    }
    __syncthreads();
  }
  for (int n = t; n < N_NODES; n += 1024) g_avail[n] = avail[n];
}

// ---------- K17: fused partial sums (take over edges, avail over nodes) ----------
__global__ void k_parts(const unsigned char* __restrict__ take, const int* __restrict__ g_avail,
                        unsigned* __restrict__ tpart, unsigned* __restrict__ apart) {
  __shared__ unsigned s[256];
  int t = threadIdx.x;
  int b = blockIdx.x;
  unsigned c = 0;
  if (b < NBLK) {
    int base = b * BE;
    for (int j = t; j < BE; j += 256) { int idx = base + j; if (idx < N_EDGES) c += take[idx]; }
  } else {
    int base = (b - NBLK) * BE;
    for (int j = t; j < BE; j += 256) { int idx = base + j; if (idx < N_NODES) c += (unsigned)g_avail[idx]; }
  }
  s[t] = c; __syncthreads();
  for (int off = 128; off > 0; off >>= 1) { if (t < off) s[t] += s[t + off]; __syncthreads(); }
  if (t == 0) {
    if (b < NBLK) tpart[b] = s[0];
    else          apart[b - NBLK] = s[0];
  }
}

// ---------- K18: scan partials, compute n_matched / num_clusters ----------
__global__ void k_scan_parts(unsigned* __restrict__ tpart, unsigned* __restrict__ apart,
                             int* __restrict__ scal) {
  __shared__ unsigned arr[512];
  int t = threadIdx.x;   // 512 threads
  unsigned v = (t < NBLK) ? tpart[t] : 0u;
  arr[t] = v;
  __syncthreads();
  for (int off = 1; off < 512; off <<= 1) {
    unsigned u2 = (t >= off) ? arr[t - off] : 0u;
    __syncthreads();
    arr[t] += u2;
    __syncthreads();
  }
  unsigned excl = arr[t] - v;
  if (t < NBLK) tpart[t] = excl;
  unsigned nm = arr[511];
  __syncthreads();
  if (t == 0) {
    unsigned run = 0;
    for (int b = 0; b < NBN; ++b) { unsigned tmp = apart[b]; apart[b] = run; run += tmp; }
    scal[0] = (int)nm;            // n_matched
    scal[2] = (int)run;           // n singleton
    scal[1] = (int)(nm + run);    // num_clusters
  }
}

// ---------- K19: merged finalize (matched clusters + singletons) ----------
__global__ void k_finalize(const unsigned char* __restrict__ take, const int* __restrict__ pay,
                           const int* __restrict__ ss, const int* __restrict__ dd,
                           const float* __restrict__ e, const unsigned* __restrict__ tpart,
                           const int* __restrict__ g_avail, const unsigned* __restrict__ apart,
                           const int* __restrict__ scal, int* __restrict__ cluster,
                           int* __restrict__ clu, int* __restrict__ clv,
                           float* __restrict__ csc) {
  __shared__ unsigned arr[256];
  int t = threadIdx.x; int b = blockIdx.x;
  if (b < NBLK) {
    int base = b * BE + t * 4;
    unsigned char tk[4];
    unsigned c = 0;
    for (int j = 0; j < 4; ++j) {
      int p = base + j;
      tk[j] = (p < N_EDGES) ? take[p] : (unsigned char)0;
      c += tk[j];
    }
    arr[t] = c;
    __syncthreads();
    unsigned v = c;
    for (int off = 1; off < 256; off <<= 1) {
      unsigned u2 = (t >= off) ? arr[t - off] : 0u;
      __syncthreads();
      arr[t] += u2;
      __syncthreads();
    }
    unsigned id = tpart[b] + (arr[t] - v);
    for (int j = 0; j < 4; ++j) {
      int p = base + j;
      if (p < N_EDGES && tk[j]) {
        int s = ss[p], d = dd[p];
        int u = min(s, d), w = max(s, d);
        cluster[s] = (int)id; cluster[d] = (int)id;
        clu[id] = u; clv[id] = w;
        csc[id] = e[pay[p]];
        ++id;
      }
    }
  } else {
    int bb = b - NBLK;
    int base = bb * BE + t * 4;
    unsigned char av[4];
    unsigned c = 0;
    for (int j = 0; j < 4; ++j) {
      int n = base + j;
      av[j] = (n < N_NODES) ? (unsigned char)g_avail[n] : (unsigned char)0;
      c += av[j];
    }
    arr[t] = c;
    __syncthreads();
    unsigned v = c;
    for (int off = 1; off < 256; off <<= 1) {
      unsigned u2 = (t >= off) ? arr[t - off] : 0u;
      __syncthreads();
      arr[t] += u2;
      __syncthreads();
    }
    unsigned id = (unsigned)scal[0] + apart[bb] + (arr[t] - v);
    for (int j = 0; j < 4; ++j) {
      int n = base + j;
      if (n < N_NODES && av[j]) {
        cluster[n] = (int)id;
        clu[id] = n; clv[id] = n;
        csc[id] = 1.0f;
        ++id;
      }
    }
  }
}

// ---------- outputs ----------
__global__ void k_out_x(const float* __restrict__ x, const int* __restrict__ clu,
                        const int* __restrict__ clv, const float* __restrict__ csc,
                        const int* __restrict__ scal, float* __restrict__ out) {
  int c = blockIdx.x; int t = threadIdx.x;
  int nc = scal[1];
  float v = 0.f;
  if (c < nc) {
    int u = clu[c], w = clv[c];
    float a = x[(size_t)u * CDIM + t];
    if (w != u) a = __fadd_rn(a, x[(size_t)w * CDIM + t]);
    v = __fmul_rn(a, csc[c]);
  }
  out[OFF_X + (size_t)c * CDIM + t] = v;
}

// merged: new_edge_index + cluster + new_batch + num_clusters
__global__ void k_out_er(const int* __restrict__ ei, const int* __restrict__ cluster,
                         const int* __restrict__ clv, const int* __restrict__ batch,
                         const int* __restrict__ scal, float* __restrict__ out) {
  int i = blockIdx.x * blockDim.x + threadIdx.x;
  if (i < 2 * N_EDGES) out[OFF_EI + i] = (float)cluster[ei[i]];
  if (i < N_NODES) {
    int nc = scal[1];
    out[OFF_CL + i] = (float)cluster[i];
    out[OFF_B + i] = (i < nc) ? (float)batch[clv[i]] : 0.0f;
    if (i == 0) out[OFF_NC] = (float)nc;
  }
}

extern "C" void kernel_launch(void* const* d_in, const int* in_sizes, int n_in,
                              void* d_out, int out_size, void* d_ws, size_t ws_size,
                              hipStream_t stream) {
  const float* x     = (const float*)d_in[0];
  const int*   ei    = (const int*)d_in[1];
  const int*   batch = (const int*)d_in[2];
  const float* lw    = (const float*)d_in[3];
  const float* lb    = (const float*)d_in[4];
  float* out = (float*)d_out;

  int* w = (int*)d_ws;
  size_t off = 0;
  auto alloc = [&](size_t n) { int* p = w + off; off += n; return p; };
  float*    p1    = (float*)alloc(N_NODES);
  float*    p2    = (float*)alloc(N_NODES);
  float*    e     = (float*)alloc(N_EDGES);
  unsigned* keyA  = (unsigned*)alloc(N_EDGES);
  unsigned* keyB  = (unsigned*)alloc(N_EDGES);
  int*      payA  = (int*)alloc(N_EDGES);
  int*      payB  = (int*)alloc(N_EDGES);
  int*      ss    = (int*)alloc(N_EDGES);
  int*      dd    = (int*)alloc(N_EDGES);
  unsigned* hist  = (unsigned*)alloc(256 * NBLK);
  off = (off + 1) & ~(size_t)1;   // align to 8B for uint64 worklist
  unsigned long long* wl = (unsigned long long*)alloc(2 * N_EDGES);
  unsigned char* take = (unsigned char*)alloc(N_EDGES / 4);
  int*      cluster = (int*)alloc(N_NODES);
  int*      clu   = (int*)alloc(N_NODES);
  int*      clv   = (int*)alloc(N_NODES);
  float*    csc   = (float*)alloc(N_NODES);
  int*      g_avail = (int*)alloc(N_NODES);
  unsigned* tpart = (unsigned*)alloc(NBLK + 1);
  unsigned* apart = (unsigned*)alloc(NBN + 1);
  int*      scal  = (int*)alloc(16);

  // scores + pass-0 histogram (fused)
  k_node_dots<<<(N_NODES + 255) / 256, 256, 0, stream>>>(x, lw, p1, p2);
  k_edge_scores_hist<<<NBLK, 256, 0, stream>>>(ei, p1, p2, lb, e, keyA, payA, hist);

  // stable LSD radix sort, 4 passes: A->B->A->B->(final fused)
  // pass 0 (shift 0): A -> B
  k_radix_scan<<<1, 256, 0, stream>>>(hist);
  k_radix_scatter<<<NBLK, 256, 0, stream>>>(keyA, payA, N_EDGES, 0, hist, keyB, payB);
  // pass 1 (shift 8): B -> A
  k_radix_hist<<<NBLK, 256, 0, stream>>>(keyB, N_EDGES, 8, hist);
  k_radix_scan<<<1, 256, 0, stream>>>(hist);
  k_radix_scatter<<<NBLK, 256, 0, stream>>>(keyB, payB, N_EDGES, 8, hist, keyA, payA);
  // pass 2 (shift 16): A -> B
  k_radix_hist<<<NBLK, 256, 0, stream>>>(keyA, N_EDGES, 16, hist);
  k_radix_scan<<<1, 256, 0, stream>>>(hist);
  k_radix_scatter<<<NBLK, 256, 0, stream>>>(keyA, payA, N_EDGES, 16, hist, keyB, payB);
  // pass 3 (shift 24): B -> final (pay + endpoints + worklist + take, fused)
  k_radix_hist<<<NBLK, 256, 0, stream>>>(keyB, N_EDGES, 24, hist);
  k_radix_scan<<<1, 256, 0, stream>>>(hist);
  k_radix_scatter_final<<<NBLK, 256, 0, stream>>>(keyB, payB, N_EDGES, 24, hist, ei,
                                                  payA, ss, dd, wl, take);

  k_match<<<1, 1024, 0, stream>>>(wl, take, g_avail);

  k_parts<<<NBLK + NBN, 256, 0, stream>>>(take, g_avail, tpart, apart);
  k_scan_parts<<<1, 512, 0, stream>>>(tpart, apart, scal);
  k_finalize<<<NBLK + NBN, 256, 0, stream>>>(take, payA, ss, dd, e, tpart,
                                             g_avail, apart, scal, cluster, clu, clv, csc);

  k_out_x<<<N_NODES, CDIM, 0, stream>>>(x, clu, clv, csc, scal, out);
  k_out_er<<<(2 * N_EDGES + 255) / 256, 256, 0, stream>>>(ei, cluster, clv, batch, scal, out);
}

// Round 13
// 1406.509 us; speedup vs baseline: 1.3112x; 1.3112x over previous
//
#include <hip/hip_runtime.h>

#define N_NODES 20000
#define N_EDGES 320000
#define CDIM    256
#define BE      1024
#define NBLK    313      // ceil(N_EDGES/BE)
#define NBN     20       // ceil(N_NODES/BE)
#define CH      8192     // serial-match chunk size
#define NGRP    (CH/64)  // 128 raw groups per chunk
#define NCH     ((N_EDGES + CH - 1) / CH)   // 40

#define OFF_X   0
#define OFF_EI  (N_NODES*CDIM)                 // 5120000
#define OFF_CL  (OFF_EI + 2*N_EDGES)           // 5760000
#define OFF_B   (OFF_CL + N_NODES)             // 5780000
#define OFF_NC  (OFF_B + N_NODES)              // 5800000

// ---------- XLA CPU tanh: rational approximation, plain mul/add f32 ----------
__device__ __forceinline__ float xla_tanh(float x) {
  float ax = fabsf(x);
  float xc = fminf(fmaxf(x, -9.0f), 9.0f);
  float x2 = __fmul_rn(xc, xc);
  float p = -2.76076847742355e-16f;
  p = __fadd_rn(__fmul_rn(p, x2), 2.00018790482477e-13f);
  p = __fadd_rn(__fmul_rn(p, x2), -8.60467152213735e-11f);
  p = __fadd_rn(__fmul_rn(p, x2), 5.12229709037114e-08f);
  p = __fadd_rn(__fmul_rn(p, x2), 1.48572235717979e-05f);
  p = __fadd_rn(__fmul_rn(p, x2), 6.37261928875436e-04f);
  p = __fadd_rn(__fmul_rn(p, x2), 4.89352455891786e-03f);
  float num = __fmul_rn(xc, p);
  float q = 1.19825839466702e-06f;
  q = __fadd_rn(__fmul_rn(q, x2), 1.18534705686654e-04f);
  q = __fadd_rn(__fmul_rn(q, x2), 2.26843463243900e-03f);
  q = __fadd_rn(__fmul_rn(q, x2), 4.89352518554385e-03f);
  float r = num / q;   // correctly-rounded f32 divide
  return (ax < 0.0004f) ? x : r;
}

// ---------- K0: per-node partial dots, sequential-k mul+add chain ----------
__global__ void k_node_dots(const float* __restrict__ x, const float* __restrict__ w,
                            float* __restrict__ p1, float* __restrict__ p2) {
  __shared__ float sw[2*CDIM];
  for (int i = threadIdx.x; i < 2*CDIM; i += blockDim.x) sw[i] = w[i];
  __syncthreads();
  int n = blockIdx.x * blockDim.x + threadIdx.x;
  if (n >= N_NODES) return;
  const float* row = x + (size_t)n * CDIM;
  float a1 = 0.f, a2 = 0.f;
  for (int k = 0; k < CDIM; ++k) {
    float xv = row[k];
    a1 = __fadd_rn(a1, __fmul_rn(xv, sw[k]));
    a2 = __fadd_rn(a2, __fmul_rn(xv, sw[CDIM + k]));
  }
  p1[n] = a1; p2[n] = a2;
}

// ---------- K1: edge scores + sort keys + FUSED pass-0 histogram ----------
__global__ void k_edge_scores_hist(const int* __restrict__ ei, const float* __restrict__ p1,
                                   const float* __restrict__ p2, const float* __restrict__ lb,
                                   float* __restrict__ e, unsigned* __restrict__ keyA,
                                   int* __restrict__ payA, unsigned* __restrict__ hist) {
  __shared__ unsigned h[256];
  int t = threadIdx.x;
  h[t] = 0;
  __syncthreads();
  int base = blockIdx.x * BE;
  for (int j = t; j < BE; j += 256) {
    int i = base + j;
    if (i >= N_EDGES) continue;
    int s = ei[i], d = ei[N_EDGES + i];
    float z = __fadd_rn(__fadd_rn(p1[s], p2[d]), lb[0]);
    float ev = __fadd_rn(xla_tanh(z), 0.5f);
    e[i] = ev;
    unsigned u = __float_as_uint(ev);
    u = (u >> 31) ? ~u : (u | 0x80000000u);   // ascending-order bits of e
    unsigned key = ~u;                         // ascending key == descending e
    keyA[i] = key;
    payA[i] = i;
    atomicAdd(&h[key & 255u], 1u);
  }
  __syncthreads();
  hist[t * NBLK + blockIdx.x] = h[t];
}

// ---------- radix sort (stable LSD, 4x8 bits) ----------
__global__ void k_radix_hist(const unsigned* __restrict__ key, int n, int shift,
                             unsigned* __restrict__ hist) {
  __shared__ unsigned h[256];
  int t = threadIdx.x;
  h[t] = 0;
  __syncthreads();
  int base = blockIdx.x * BE;
  for (int j = t; j < BE; j += 256) {
    int idx = base + j;
    if (idx < n) atomicAdd(&h[(key[idx] >> shift) & 255u], 1u);
  }
  __syncthreads();
  hist[t * NBLK + blockIdx.x] = h[t];
}

// parallel scan: 4 threads per bin, each owns ~1/4 of the 313 blocks.
// phase1 quarter sums -> per-bin totals -> 256-bin ladder scan -> 4-way writeback.
__global__ __launch_bounds__(1024) void k_radix_scan(unsigned* __restrict__ hist) {
  __shared__ unsigned qsum[1024];
  __shared__ unsigned bsum[256];
  __shared__ unsigned arr[256];
  int t = threadIdx.x;
  int bin = t >> 2, q = t & 3;
  int qs = (NBLK * q) >> 2, qe = (NBLK * (q + 1)) >> 2;
  unsigned sum = 0;
  for (int b = qs; b < qe; ++b) sum += hist[bin * NBLK + b];
  qsum[t] = sum;
  __syncthreads();
  if (q == 0) {
    bsum[bin] = qsum[bin * 4] + qsum[bin * 4 + 1] + qsum[bin * 4 + 2] + qsum[bin * 4 + 3];
  }
  __syncthreads();
  if (t < 256) arr[t] = bsum[t];
  __syncthreads();
  for (int off = 1; off < 256; off <<= 1) {
    unsigned u = 0;
    if (t < 256 && t >= off) u = arr[t - off];
    __syncthreads();
    if (t < 256) arr[t] += u;
    __syncthreads();
  }
  // arr[bin] = inclusive sum over bins <= bin
  unsigned qex = 0;
  for (int k = 0; k < q; ++k) qex += qsum[bin * 4 + k];
  unsigned run = (arr[bin] - bsum[bin]) + qex;
  for (int b = qs; b < qe; ++b) {
    unsigned tmp = hist[bin * NBLK + b];
    hist[bin * NBLK + b] = run;
    run += tmp;
  }
}

__global__ void k_radix_scatter(const unsigned* __restrict__ key, const int* __restrict__ pay,
                                int n, int shift, const unsigned* __restrict__ hist,
                                unsigned* __restrict__ keyo, int* __restrict__ payo) {
  __shared__ unsigned mask[256][8];
  __shared__ unsigned rbase[256];
  int t = threadIdx.x;
  rbase[t] = hist[t * NBLK + blockIdx.x];
  __syncthreads();
  int base = blockIdx.x * BE;
  for (int tile = 0; tile < BE / 256; ++tile) {
    for (int wq = 0; wq < 8; ++wq) mask[t][wq] = 0u;
    __syncthreads();
    int idx = base + tile * 256 + t;
    unsigned k = 0; int bin = 0; int valid = (idx < n);
    if (valid) {
      k = key[idx];
      bin = (k >> shift) & 255;
      atomicOr(&mask[bin][t >> 5], 1u << (t & 31));
    }
    __syncthreads();
    if (valid) {
      int w = t >> 5;
      unsigned r = 0;
      for (int w2 = 0; w2 < w; ++w2) r += __popc(mask[bin][w2]);
      r += __popc(mask[bin][w] & ((1u << (t & 31)) - 1u));
      unsigned pos = rbase[bin] + r;
      keyo[pos] = k;
      payo[pos] = pay[idx];
    }
    __syncthreads();
    unsigned c = 0;
    for (int wq = 0; wq < 8; ++wq) c += __popc(mask[t][wq]);
    rbase[t] += c;
    __syncthreads();
  }
}

// ---------- final scatter pass FUSED with endpoint gather / worklist build ----
__global__ void k_radix_scatter_final(const unsigned* __restrict__ key, const int* __restrict__ pay,
                                      int n, int shift, const unsigned* __restrict__ hist,
                                      const int* __restrict__ ei, int* __restrict__ payo,
                                      int* __restrict__ ss, int* __restrict__ dd,
                                      unsigned long long* __restrict__ wl,
                                      unsigned char* __restrict__ take) {
  __shared__ unsigned mask[256][8];
  __shared__ unsigned rbase[256];
  int t = threadIdx.x;
  rbase[t] = hist[t * NBLK + blockIdx.x];
  __syncthreads();
  int base = blockIdx.x * BE;
  for (int tile = 0; tile < BE / 256; ++tile) {
    for (int wq = 0; wq < 8; ++wq) mask[t][wq] = 0u;
    __syncthreads();
    int idx = base + tile * 256 + t;
    unsigned k = 0; int bin = 0; int valid = (idx < n);
    if (valid) {
      k = key[idx];
      bin = (k >> shift) & 255;
      atomicOr(&mask[bin][t >> 5], 1u << (t & 31));
    }
    __syncthreads();
    if (valid) {
      int w = t >> 5;
      unsigned r = 0;
      for (int w2 = 0; w2 < w; ++w2) r += __popc(mask[bin][w2]);
      r += __popc(mask[bin][w] & ((1u << (t & 31)) - 1u));
      unsigned pos = rbase[bin] + r;
      int o = pay[idx];
      int s = ei[o];
      int d = ei[N_EDGES + o];
      payo[pos] = o;
      ss[pos] = s;
      dd[pos] = d;
      wl[pos] = ((unsigned long long)pos << 30) | ((unsigned long long)(unsigned)s << 15)
              | (unsigned long long)(unsigned)d;
      take[pos] = 0;
    }
    __syncthreads();
    unsigned c = 0;
    for (int wq = 0; wq < 8; ++wq) c += __popc(mask[t][wq]);
    rbase[t] += c;
    __syncthreads();
  }
}

// ---------- K16: persistent single-block EXACT sequential greedy matching ----------
// R8 version verbatim (best measured: 828us). Chunked over the sorted list:
//  1) 16 waves stage + alive-check, order-preserving compaction into LDS.
//  2) 16 waves build per-edge intra-group kill-masks (LDS broadcast inner loop).
//  3) Wave 0 walks groups in order: avail recheck, ballot, then per-take
//     j=ffs(am); tk|=1<<j; am&=~readlane(km,j)  (no re-ballot).
// Take-set == sequential greedy -> outputs bit-identical.
__global__ __launch_bounds__(1024) void k_match(const unsigned long long* __restrict__ wl,
                                                unsigned char* __restrict__ take,
                                                int* __restrict__ g_avail) {
  __shared__ unsigned char avail[N_NODES];          // 20000 B
  __shared__ unsigned long long comp[CH];           // 65536 B
  __shared__ unsigned long long kmask[CH];          // 65536 B
  __shared__ unsigned gcnt[NGRP];                   // 512 B
  __shared__ unsigned gbase[NGRP];                  // 512 B
  __shared__ int s_ncomp;
  int t = threadIdx.x;
  int lane = t & 63, wid = t >> 6;
  unsigned long long lmask_lt = (lane == 0) ? 0ull : (~0ull >> (64 - lane));
  for (int n = t; n < N_NODES; n += 1024) avail[n] = 1;
  __syncthreads();
  for (int c = 0; c < NCH; ++c) {
    int base = c * CH;
    // --- 1a) stage + alive-count (wave wid owns raw groups wid*8 .. wid*8+7)
    unsigned long long myv[8];
    unsigned char myal[8];
    for (int it = 0; it < 8; ++it) {
      int rg = wid * 8 + it;
      int i = base + rg * 64 + lane;
      unsigned long long v = (i < N_EDGES) ? wl[i] : 0ull;
      bool a = false;
      if (i < N_EDGES) {
        int d = (int)(v & 0x7FFFu);
        int s = (int)((v >> 15) & 0x7FFFu);
        a = avail[s] && avail[d];
      }
      myv[it] = v; myal[it] = a ? 1 : 0;
      unsigned long long bal = __ballot(a);
      if (lane == 0) gcnt[rg] = (unsigned)__popcll(bal);
    }
    __syncthreads();
    // --- 1b) exclusive scan of 128 raw-group counts (wave 0)
    if (wid == 0) {
      unsigned a0 = gcnt[lane], a1 = gcnt[64 + lane];
      unsigned s0 = a0;
      for (int o = 1; o < 64; o <<= 1) { unsigned u = __shfl_up(s0, o); if (lane >= o) s0 += u; }
      unsigned tot0 = __shfl(s0, 63);
      unsigned s1 = a1;
      for (int o = 1; o < 64; o <<= 1) { unsigned u = __shfl_up(s1, o); if (lane >= o) s1 += u; }
      gbase[lane] = s0 - a0;
      gbase[64 + lane] = tot0 + s1 - a1;
      if (lane == 63) s_ncomp = (int)(tot0 + s1);
    }
    __syncthreads();
    // --- 1c) order-preserving writeback of alive edges
    for (int it = 0; it < 8; ++it) {
      int rg = wid * 8 + it;
      unsigned long long bal = __ballot(myal[it] != 0);
      if (myal[it]) {
        unsigned r = (unsigned)__popcll(bal & lmask_lt);
        comp[gbase[rg] + r] = myv[it];
      }
    }
    __syncthreads();
    int ncomp = s_ncomp;
    // --- 2) kill-mask build over compacted groups (16 waves round-robin)
    for (int g = wid; g * 64 < ncomp; g += 16) {
      int i = g * 64 + lane;
      unsigned long long v = (i < ncomp) ? comp[i] : 0ull;
      int d = (int)(v & 0x7FFFu);
      int s = (int)((v >> 15) & 0x7FFFu);
      unsigned long long km = 1ull << lane;   // self bit
      if (i < ncomp) {
        int glen = ncomp - g * 64; if (glen > 64) glen = 64;
        for (int j = lane + 1; j < glen; ++j) {
          unsigned long long vj = comp[g * 64 + j];   // broadcast read
          int dj = (int)(vj & 0x7FFFu);
          int sj = (int)((vj >> 15) & 0x7FFFu);
          if (sj == s || sj == d || dj == s || dj == d) km |= 1ull << j;
        }
      }
      kmask[i] = km;
    }
    __syncthreads();
    // --- 3) wave-0 exact serial walk (readlane-based take loop)
    if (wid == 0) {
      for (int g = 0; g * 64 < ncomp; ++g) {
        int i = g * 64 + lane;
        unsigned long long v = (i < ncomp) ? comp[i] : 0ull;
        int d = (int)(v & 0x7FFFu);
        int s = (int)((v >> 15) & 0x7FFFu);
        unsigned long long km = (i < ncomp) ? kmask[i] : 0ull;
        unsigned km_lo = (unsigned)km;
        unsigned km_hi = (unsigned)(km >> 32);
        bool alive = (i < ncomp) && avail[s] && avail[d];
        unsigned long long am = __ballot(alive);
        unsigned long long tk = 0;
        while (am) {
          int j = __ffsll((long long)am) - 1;
          tk |= 1ull << j;
          unsigned long long kj =
              ((unsigned long long)(unsigned)__builtin_amdgcn_readlane((int)km_hi, j) << 32)
            | (unsigned long long)(unsigned)__builtin_amdgcn_readlane((int)km_lo, j);
          am &= ~kj;   // kills j itself + later same-endpoint edges in group
        }
        if ((tk >> lane) & 1ull) {
          take[(unsigned)(v >> 30)] = 1;
          avail[s] = 0; avail[d] = 0;
        }
      }
    }
    __syncthreads();
  }
  for (int n = t; n < N_NODES; n += 1024) g_avail[n] = avail[n];
}

// ---------- K17: fused partial sums (take over edges, avail over nodes) ----------
__global__ void k_parts(const unsigned char* __restrict__ take, const int* __restrict__ g_avail,
                        unsigned* __restrict__ tpart, unsigned* __restrict__ apart) {
  __shared__ unsigned s[256];
  int t = threadIdx.x;
  int b = blockIdx.x;
  unsigned c = 0;
  if (b < NBLK) {
    int base = b * BE;
    for (int j = t; j < BE; j += 256) { int idx = base + j; if (idx < N_EDGES) c += take[idx]; }
  } else {
    int base = (b - NBLK) * BE;
    for (int j = t; j < BE; j += 256) { int idx = base + j; if (idx < N_NODES) c += (unsigned)g_avail[idx]; }
  }
  s[t] = c; __syncthreads();
  for (int off = 128; off > 0; off >>= 1) { if (t < off) s[t] += s[t + off]; __syncthreads(); }
  if (t == 0) {
    if (b < NBLK) tpart[b] = s[0];
    else          apart[b - NBLK] = s[0];
  }
}

// ---------- K18: scan partials, compute n_matched / num_clusters ----------
__global__ void k_scan_parts(unsigned* __restrict__ tpart, unsigned* __restrict__ apart,
                             int* __restrict__ scal) {
  __shared__ unsigned arr[512];
  int t = threadIdx.x;   // 512 threads
  unsigned v = (t < NBLK) ? tpart[t] : 0u;
  arr[t] = v;
  __syncthreads();
  for (int off = 1; off < 512; off <<= 1) {
    unsigned u2 = (t >= off) ? arr[t - off] : 0u;
    __syncthreads();
    arr[t] += u2;
    __syncthreads();
  }
  unsigned excl = arr[t] - v;
  if (t < NBLK) tpart[t] = excl;
  unsigned nm = arr[511];
  __syncthreads();
  if (t == 0) {
    unsigned run = 0;
    for (int b = 0; b < NBN; ++b) { unsigned tmp = apart[b]; apart[b] = run; run += tmp; }
    scal[0] = (int)nm;            // n_matched
    scal[2] = (int)run;           // n singleton
    scal[1] = (int)(nm + run);    // num_clusters
  }
}

// ---------- K19: merged finalize (matched clusters + singletons) ----------
__global__ void k_finalize(const unsigned char* __restrict__ take, const int* __restrict__ pay,
                           const int* __restrict__ ss, const int* __restrict__ dd,
                           const float* __restrict__ e, const unsigned* __restrict__ tpart,
                           const int* __restrict__ g_avail, const unsigned* __restrict__ apart,
                           const int* __restrict__ scal, int* __restrict__ cluster,
                           int* __restrict__ clu, int* __restrict__ clv,
                           float* __restrict__ csc) {
  __shared__ unsigned arr[256];
  int t = threadIdx.x; int b = blockIdx.x;
  if (b < NBLK) {
    int base = b * BE + t * 4;
    unsigned char tk[4];
    unsigned c = 0;
    for (int j = 0; j < 4; ++j) {
      int p = base + j;
      tk[j] = (p < N_EDGES) ? take[p] : (unsigned char)0;
      c += tk[j];
    }
    arr[t] = c;
    __syncthreads();
    unsigned v = c;
    for (int off = 1; off < 256; off <<= 1) {
      unsigned u2 = (t >= off) ? arr[t - off] : 0u;
      __syncthreads();
      arr[t] += u2;
      __syncthreads();
    }
    unsigned id = tpart[b] + (arr[t] - v);
    for (int j = 0; j < 4; ++j) {
      int p = base + j;
      if (p < N_EDGES && tk[j]) {
        int s = ss[p], d = dd[p];
        int u = min(s, d), w = max(s, d);
        cluster[s] = (int)id; cluster[d] = (int)id;
        clu[id] = u; clv[id] = w;
        csc[id] = e[pay[p]];
        ++id;
      }
    }
  } else {
    int bb = b - NBLK;
    int base = bb * BE + t * 4;
    unsigned char av[4];
    unsigned c = 0;
    for (int j = 0; j < 4; ++j) {
      int n = base + j;
      av[j] = (n < N_NODES) ? (unsigned char)g_avail[n] : (unsigned char)0;
      c += av[j];
    }
    arr[t] = c;
    __syncthreads();
    unsigned v = c;
    for (int off = 1; off < 256; off <<= 1) {
      unsigned u2 = (t >= off) ? arr[t - off] : 0u;
      __syncthreads();
      arr[t] += u2;
      __syncthreads();
    }
    unsigned id = (unsigned)scal[0] + apart[bb] + (arr[t] - v);
    for (int j = 0; j < 4; ++j) {
      int n = base + j;
      if (n < N_NODES && av[j]) {
        cluster[n] = (int)id;
        clu[id] = n; clv[id] = n;
        csc[id] = 1.0f;
        ++id;
      }
    }
  }
}

// ---------- outputs ----------
__global__ void k_out_x(const float* __restrict__ x, const int* __restrict__ clu,
                        const int* __restrict__ clv, const float* __restrict__ csc,
                        const int* __restrict__ scal, float* __restrict__ out) {
  int c = blockIdx.x; int t = threadIdx.x;
  int nc = scal[1];
  float v = 0.f;
  if (c < nc) {
    int u = clu[c], w = clv[c];
    float a = x[(size_t)u * CDIM + t];
    if (w != u) a = __fadd_rn(a, x[(size_t)w * CDIM + t]);
    v = __fmul_rn(a, csc[c]);
  }
  out[OFF_X + (size_t)c * CDIM + t] = v;
}

// merged: new_edge_index + cluster + new_batch + num_clusters
__global__ void k_out_er(const int* __restrict__ ei, const int* __restrict__ cluster,
                         const int* __restrict__ clv, const int* __restrict__ batch,
                         const int* __restrict__ scal, float* __restrict__ out) {
  int i = blockIdx.x * blockDim.x + threadIdx.x;
  if (i < 2 * N_EDGES) out[OFF_EI + i] = (float)cluster[ei[i]];
  if (i < N_NODES) {
    int nc = scal[1];
    out[OFF_CL + i] = (float)cluster[i];
    out[OFF_B + i] = (i < nc) ? (float)batch[clv[i]] : 0.0f;
    if (i == 0) out[OFF_NC] = (float)nc;
  }
}

extern "C" void kernel_launch(void* const* d_in, const int* in_sizes, int n_in,
                              void* d_out, int out_size, void* d_ws, size_t ws_size,
                              hipStream_t stream) {
  const float* x     = (const float*)d_in[0];
  const int*   ei    = (const int*)d_in[1];
  const int*   batch = (const int*)d_in[2];
  const float* lw    = (const float*)d_in[3];
  const float* lb    = (const float*)d_in[4];
  float* out = (float*)d_out;

  int* w = (int*)d_ws;
  size_t off = 0;
  auto alloc = [&](size_t n) { int* p = w + off; off += n; return p; };
  float*    p1    = (float*)alloc(N_NODES);
  float*    p2    = (float*)alloc(N_NODES);
  float*    e     = (float*)alloc(N_EDGES);
  unsigned* keyA  = (unsigned*)alloc(N_EDGES);
  unsigned* keyB  = (unsigned*)alloc(N_EDGES);
  int*      payA  = (int*)alloc(N_EDGES);
  int*      payB  = (int*)alloc(N_EDGES);
  int*      ss    = (int*)alloc(N_EDGES);
  int*      dd    = (int*)alloc(N_EDGES);
  unsigned* hist  = (unsigned*)alloc(256 * NBLK);
  off = (off + 1) & ~(size_t)1;   // align to 8B for uint64 worklist
  unsigned long long* wl = (unsigned long long*)alloc(2 * N_EDGES);
  unsigned char* take = (unsigned char*)alloc(N_EDGES / 4);
  int*      cluster = (int*)alloc(N_NODES);
  int*      clu   = (int*)alloc(N_NODES);
  int*      clv   = (int*)alloc(N_NODES);
  float*    csc   = (float*)alloc(N_NODES);
  int*      g_avail = (int*)alloc(N_NODES);
  unsigned* tpart = (unsigned*)alloc(NBLK + 1);
  unsigned* apart = (unsigned*)alloc(NBN + 1);
  int*      scal  = (int*)alloc(16);

  // scores + pass-0 histogram (fused)
  k_node_dots<<<(N_NODES + 255) / 256, 256, 0, stream>>>(x, lw, p1, p2);
  k_edge_scores_hist<<<NBLK, 256, 0, stream>>>(ei, p1, p2, lb, e, keyA, payA, hist);

  // stable LSD radix sort, 4 passes: A->B->A->B->(final fused)
  k_radix_scan<<<1, 1024, 0, stream>>>(hist);
  k_radix_scatter<<<NBLK, 256, 0, stream>>>(keyA, payA, N_EDGES, 0, hist, keyB, payB);
  k_radix_hist<<<NBLK, 256, 0, stream>>>(keyB, N_EDGES, 8, hist);
  k_radix_scan<<<1, 1024, 0, stream>>>(hist);
  k_radix_scatter<<<NBLK, 256, 0, stream>>>(keyB, payB, N_EDGES, 8, hist, keyA, payA);
  k_radix_hist<<<NBLK, 256, 0, stream>>>(keyA, N_EDGES, 16, hist);
  k_radix_scan<<<1, 1024, 0, stream>>>(hist);
  k_radix_scatter<<<NBLK, 256, 0, stream>>>(keyA, payA, N_EDGES, 16, hist, keyB, payB);
  k_radix_hist<<<NBLK, 256, 0, stream>>>(keyB, N_EDGES, 24, hist);
  k_radix_scan<<<1, 1024, 0, stream>>>(hist);
  k_radix_scatter_final<<<NBLK, 256, 0, stream>>>(keyB, payB, N_EDGES, 24, hist, ei,
                                                  payA, ss, dd, wl, take);

  k_match<<<1, 1024, 0, stream>>>(wl, take, g_avail);

  k_parts<<<NBLK + NBN, 256, 0, stream>>>(take, g_avail, tpart, apart);
  k_scan_parts<<<1, 512, 0, stream>>>(tpart, apart, scal);
  k_finalize<<<NBLK + NBN, 256, 0, stream>>>(take, payA, ss, dd, e, tpart,
                                             g_avail, apart, scal, cluster, clu, clv, csc);

  k_out_x<<<N_NODES, CDIM, 0, stream>>>(x, clu, clv, csc, scal, out);
  k_out_er<<<(2 * N_EDGES + 255) / 256, 256, 0, stream>>>(ei, cluster, clv, batch, scal, out);
}

// Round 14
// 1090.955 us; speedup vs baseline: 1.6905x; 1.2892x over previous
//
#include <hip/hip_runtime.h>

#define N_NODES 20000
#define N_EDGES 320000
#define CDIM    256
#define BE      1024
#define NBLK    313      // ceil(N_EDGES/BE)
#define NBN     20       // ceil(N_NODES/BE)
#define CH      8192     // serial-match chunk size
#define NGRP    (CH/64)  // 128 raw groups per chunk
#define NCH     ((N_EDGES + CH - 1) / CH)   // 40

#define OFF_X   0
#define OFF_EI  (N_NODES*CDIM)                 // 5120000
#define OFF_CL  (OFF_EI + 2*N_EDGES)           // 5760000
#define OFF_B   (OFF_CL + N_NODES)             // 5780000
#define OFF_NC  (OFF_B + N_NODES)              // 5800000

// ---------- XLA CPU tanh: rational approximation, plain mul/add f32 ----------
__device__ __forceinline__ float xla_tanh(float x) {
  float ax = fabsf(x);
  float xc = fminf(fmaxf(x, -9.0f), 9.0f);
  float x2 = __fmul_rn(xc, xc);
  float p = -2.76076847742355e-16f;
  p = __fadd_rn(__fmul_rn(p, x2), 2.00018790482477e-13f);
  p = __fadd_rn(__fmul_rn(p, x2), -8.60467152213735e-11f);
  p = __fadd_rn(__fmul_rn(p, x2), 5.12229709037114e-08f);
  p = __fadd_rn(__fmul_rn(p, x2), 1.48572235717979e-05f);
  p = __fadd_rn(__fmul_rn(p, x2), 6.37261928875436e-04f);
  p = __fadd_rn(__fmul_rn(p, x2), 4.89352455891786e-03f);
  float num = __fmul_rn(xc, p);
  float q = 1.19825839466702e-06f;
  q = __fadd_rn(__fmul_rn(q, x2), 1.18534705686654e-04f);
  q = __fadd_rn(__fmul_rn(q, x2), 2.26843463243900e-03f);
  q = __fadd_rn(__fmul_rn(q, x2), 4.89352518554385e-03f);
  float r = num / q;   // correctly-rounded f32 divide
  return (ax < 0.0004f) ? x : r;
}

// ---------- K0: per-node partial dots, sequential-k mul+add chain ----------
__global__ void k_node_dots(const float* __restrict__ x, const float* __restrict__ w,
                            float* __restrict__ p1, float* __restrict__ p2) {
  __shared__ float sw[2*CDIM];
  for (int i = threadIdx.x; i < 2*CDIM; i += blockDim.x) sw[i] = w[i];
  __syncthreads();
  int n = blockIdx.x * blockDim.x + threadIdx.x;
  if (n >= N_NODES) return;
  const float* row = x + (size_t)n * CDIM;
  float a1 = 0.f, a2 = 0.f;
  for (int k = 0; k < CDIM; ++k) {
    float xv = row[k];
    a1 = __fadd_rn(a1, __fmul_rn(xv, sw[k]));
    a2 = __fadd_rn(a2, __fmul_rn(xv, sw[CDIM + k]));
  }
  p1[n] = a1; p2[n] = a2;
}

// ---------- K1: edge scores + sort keys + FUSED pass-0 histogram ----------
__global__ void k_edge_scores_hist(const int* __restrict__ ei, const float* __restrict__ p1,
                                   const float* __restrict__ p2, const float* __restrict__ lb,
                                   float* __restrict__ e, unsigned* __restrict__ keyA,
                                   int* __restrict__ payA, unsigned* __restrict__ hist) {
  __shared__ unsigned h[256];
  int t = threadIdx.x;
  h[t] = 0;
  __syncthreads();
  int base = blockIdx.x * BE;
  for (int j = t; j < BE; j += 256) {
    int i = base + j;
    if (i >= N_EDGES) continue;
    int s = ei[i], d = ei[N_EDGES + i];
    float z = __fadd_rn(__fadd_rn(p1[s], p2[d]), lb[0]);
    float ev = __fadd_rn(xla_tanh(z), 0.5f);
    e[i] = ev;
    unsigned u = __float_as_uint(ev);
    u = (u >> 31) ? ~u : (u | 0x80000000u);   // ascending-order bits of e
    unsigned key = ~u;                         // ascending key == descending e
    keyA[i] = key;
    payA[i] = i;
    atomicAdd(&h[key & 255u], 1u);
  }
  __syncthreads();
  hist[t * NBLK + blockIdx.x] = h[t];
}

// ---------- radix sort (stable LSD, 4x8 bits) ----------
__global__ void k_radix_hist(const unsigned* __restrict__ key, int n, int shift,
                             unsigned* __restrict__ hist) {
  __shared__ unsigned h[256];
  int t = threadIdx.x;
  h[t] = 0;
  __syncthreads();
  int base = blockIdx.x * BE;
  for (int j = t; j < BE; j += 256) {
    int idx = base + j;
    if (idx < n) atomicAdd(&h[(key[idx] >> shift) & 255u], 1u);
  }
  __syncthreads();
  hist[t * NBLK + blockIdx.x] = h[t];
}

// R8-proven serial-per-thread scan (256 threads; loops pipeline fine in HW)
__global__ void k_radix_scan(unsigned* __restrict__ hist) {
  __shared__ unsigned sums[256];
  int t = threadIdx.x;
  unsigned rs = 0;
  for (int b = 0; b < NBLK; ++b) rs += hist[t * NBLK + b];
  sums[t] = rs;
  __syncthreads();
  for (int off = 1; off < 256; off <<= 1) {
    unsigned u2 = (t >= off) ? sums[t - off] : 0u;
    __syncthreads();
    sums[t] += u2;
    __syncthreads();
  }
  unsigned run = sums[t] - rs;   // exclusive base for bin t
  for (int b = 0; b < NBLK; ++b) {
    unsigned tmp = hist[t * NBLK + b];
    hist[t * NBLK + b] = run;
    run += tmp;
  }
}

__global__ void k_radix_scatter(const unsigned* __restrict__ key, const int* __restrict__ pay,
                                int n, int shift, const unsigned* __restrict__ hist,
                                unsigned* __restrict__ keyo, int* __restrict__ payo) {
  __shared__ unsigned mask[256][8];
  __shared__ unsigned rbase[256];
  int t = threadIdx.x;
  rbase[t] = hist[t * NBLK + blockIdx.x];
  __syncthreads();
  int base = blockIdx.x * BE;
  for (int tile = 0; tile < BE / 256; ++tile) {
    for (int wq = 0; wq < 8; ++wq) mask[t][wq] = 0u;
    __syncthreads();
    int idx = base + tile * 256 + t;
    unsigned k = 0; int bin = 0; int valid = (idx < n);
    if (valid) {
      k = key[idx];
      bin = (k >> shift) & 255;
      atomicOr(&mask[bin][t >> 5], 1u << (t & 31));
    }
    __syncthreads();
    if (valid) {
      int w = t >> 5;
      unsigned r = 0;
      for (int w2 = 0; w2 < w; ++w2) r += __popc(mask[bin][w2]);
      r += __popc(mask[bin][w] & ((1u << (t & 31)) - 1u));
      unsigned pos = rbase[bin] + r;
      keyo[pos] = k;
      payo[pos] = pay[idx];
    }
    __syncthreads();
    unsigned c = 0;
    for (int wq = 0; wq < 8; ++wq) c += __popc(mask[t][wq]);
    rbase[t] += c;
    __syncthreads();
  }
}

// ---------- final scatter pass FUSED with endpoint gather / worklist build ----
__global__ void k_radix_scatter_final(const unsigned* __restrict__ key, const int* __restrict__ pay,
                                      int n, int shift, const unsigned* __restrict__ hist,
                                      const int* __restrict__ ei, int* __restrict__ payo,
                                      int* __restrict__ ss, int* __restrict__ dd,
                                      unsigned long long* __restrict__ wl,
                                      unsigned char* __restrict__ take) {
  __shared__ unsigned mask[256][8];
  __shared__ unsigned rbase[256];
  int t = threadIdx.x;
  rbase[t] = hist[t * NBLK + blockIdx.x];
  __syncthreads();
  int base = blockIdx.x * BE;
  for (int tile = 0; tile < BE / 256; ++tile) {
    for (int wq = 0; wq < 8; ++wq) mask[t][wq] = 0u;
    __syncthreads();
    int idx = base + tile * 256 + t;
    unsigned k = 0; int bin = 0; int valid = (idx < n);
    if (valid) {
      k = key[idx];
      bin = (k >> shift) & 255;
      atomicOr(&mask[bin][t >> 5], 1u << (t & 31));
    }
    __syncthreads();
    if (valid) {
      int w = t >> 5;
      unsigned r = 0;
      for (int w2 = 0; w2 < w; ++w2) r += __popc(mask[bin][w2]);
      r += __popc(mask[bin][w] & ((1u << (t & 31)) - 1u));
      unsigned pos = rbase[bin] + r;
      int o = pay[idx];
      int s = ei[o];
      int d = ei[N_EDGES + o];
      payo[pos] = o;
      ss[pos] = s;
      dd[pos] = d;
      wl[pos] = ((unsigned long long)pos << 30) | ((unsigned long long)(unsigned)s << 15)
              | (unsigned long long)(unsigned)d;
      take[pos] = 0;
    }
    __syncthreads();
    unsigned c = 0;
    for (int wq = 0; wq < 8; ++wq) c += __popc(mask[t][wq]);
    rbase[t] += c;
    __syncthreads();
  }
}

// ---------- K16: persistent single-block EXACT sequential greedy matching ----------
// R8 version verbatim (best measured: 828us across R8-R13 variants).
__global__ __launch_bounds__(1024) void k_match(const unsigned long long* __restrict__ wl,
                                                unsigned char* __restrict__ take,
                                                int* __restrict__ g_avail) {
  __shared__ unsigned char avail[N_NODES];          // 20000 B
  __shared__ unsigned long long comp[CH];           // 65536 B
  __shared__ unsigned long long kmask[CH];          // 65536 B
  __shared__ unsigned gcnt[NGRP];                   // 512 B
  __shared__ unsigned gbase[NGRP];                  // 512 B
  __shared__ int s_ncomp;
  int t = threadIdx.x;
  int lane = t & 63, wid = t >> 6;
  unsigned long long lmask_lt = (lane == 0) ? 0ull : (~0ull >> (64 - lane));
  for (int n = t; n < N_NODES; n += 1024) avail[n] = 1;
  __syncthreads();
  for (int c = 0; c < NCH; ++c) {
    int base = c * CH;
    // --- 1a) stage + alive-count (wave wid owns raw groups wid*8 .. wid*8+7)
    unsigned long long myv[8];
    unsigned char myal[8];
    for (int it = 0; it < 8; ++it) {
      int rg = wid * 8 + it;
      int i = base + rg * 64 + lane;
      unsigned long long v = (i < N_EDGES) ? wl[i] : 0ull;
      bool a = false;
      if (i < N_EDGES) {
        int d = (int)(v & 0x7FFFu);
        int s = (int)((v >> 15) & 0x7FFFu);
        a = avail[s] && avail[d];
      }
      myv[it] = v; myal[it] = a ? 1 : 0;
      unsigned long long bal = __ballot(a);
      if (lane == 0) gcnt[rg] = (unsigned)__popcll(bal);
    }
    __syncthreads();
    // --- 1b) exclusive scan of 128 raw-group counts (wave 0)
    if (wid == 0) {
      unsigned a0 = gcnt[lane], a1 = gcnt[64 + lane];
      unsigned s0 = a0;
      for (int o = 1; o < 64; o <<= 1) { unsigned u = __shfl_up(s0, o); if (lane >= o) s0 += u; }
      unsigned tot0 = __shfl(s0, 63);
      unsigned s1 = a1;
      for (int o = 1; o < 64; o <<= 1) { unsigned u = __shfl_up(s1, o); if (lane >= o) s1 += u; }
      gbase[lane] = s0 - a0;
      gbase[64 + lane] = tot0 + s1 - a1;
      if (lane == 63) s_ncomp = (int)(tot0 + s1);
    }
    __syncthreads();
    // --- 1c) order-preserving writeback of alive edges
    for (int it = 0; it < 8; ++it) {
      int rg = wid * 8 + it;
      unsigned long long bal = __ballot(myal[it] != 0);
      if (myal[it]) {
        unsigned r = (unsigned)__popcll(bal & lmask_lt);
        comp[gbase[rg] + r] = myv[it];
      }
    }
    __syncthreads();
    int ncomp = s_ncomp;
    // --- 2) kill-mask build over compacted groups (16 waves round-robin)
    for (int g = wid; g * 64 < ncomp; g += 16) {
      int i = g * 64 + lane;
      unsigned long long v = (i < ncomp) ? comp[i] : 0ull;
      int d = (int)(v & 0x7FFFu);
      int s = (int)((v >> 15) & 0x7FFFu);
      unsigned long long km = 1ull << lane;   // self bit
      if (i < ncomp) {
        int glen = ncomp - g * 64; if (glen > 64) glen = 64;
        for (int j = lane + 1; j < glen; ++j) {
          unsigned long long vj = comp[g * 64 + j];   // broadcast read
          int dj = (int)(vj & 0x7FFFu);
          int sj = (int)((vj >> 15) & 0x7FFFu);
          if (sj == s || sj == d || dj == s || dj == d) km |= 1ull << j;
        }
      }
      kmask[i] = km;
    }
    __syncthreads();
    // --- 3) wave-0 exact serial walk (readlane-based take loop)
    if (wid == 0) {
      for (int g = 0; g * 64 < ncomp; ++g) {
        int i = g * 64 + lane;
        unsigned long long v = (i < ncomp) ? comp[i] : 0ull;
        int d = (int)(v & 0x7FFFu);
        int s = (int)((v >> 15) & 0x7FFFu);
        unsigned long long km = (i < ncomp) ? kmask[i] : 0ull;
        unsigned km_lo = (unsigned)km;
        unsigned km_hi = (unsigned)(km >> 32);
        bool alive = (i < ncomp) && avail[s] && avail[d];
        unsigned long long am = __ballot(alive);
        unsigned long long tk = 0;
        while (am) {
          int j = __ffsll((long long)am) - 1;
          tk |= 1ull << j;
          unsigned long long kj =
              ((unsigned long long)(unsigned)__builtin_amdgcn_readlane((int)km_hi, j) << 32)
            | (unsigned long long)(unsigned)__builtin_amdgcn_readlane((int)km_lo, j);
          am &= ~kj;   // kills j itself + later same-endpoint edges in group
        }
        if ((tk >> lane) & 1ull) {
          take[(unsigned)(v >> 30)] = 1;
          avail[s] = 0; avail[d] = 0;
        }
      }
    }
    __syncthreads();
  }
  for (int n = t; n < N_NODES; n += 1024) g_avail[n] = avail[n];
}

// ---------- K17: fused partial sums (take over edges, avail over nodes) ----------
__global__ void k_parts(const unsigned char* __restrict__ take, const int* __restrict__ g_avail,
                        unsigned* __restrict__ tpart, unsigned* __restrict__ apart) {
  __shared__ unsigned s[256];
  int t = threadIdx.x;
  int b = blockIdx.x;
  unsigned c = 0;
  if (b < NBLK) {
    int base = b * BE;
    for (int j = t; j < BE; j += 256) { int idx = base + j; if (idx < N_EDGES) c += take[idx]; }
  } else {
    int base = (b - NBLK) * BE;
    for (int j = t; j < BE; j += 256) { int idx = base + j; if (idx < N_NODES) c += (unsigned)g_avail[idx]; }
  }
  s[t] = c; __syncthreads();
  for (int off = 128; off > 0; off >>= 1) { if (t < off) s[t] += s[t + off]; __syncthreads(); }
  if (t == 0) {
    if (b < NBLK) tpart[b] = s[0];
    else          apart[b - NBLK] = s[0];
  }
}

// ---------- K18: scan partials, compute n_matched / num_clusters ----------
__global__ void k_scan_parts(unsigned* __restrict__ tpart, unsigned* __restrict__ apart,
                             int* __restrict__ scal) {
  __shared__ unsigned arr[512];
  int t = threadIdx.x;   // 512 threads
  unsigned v = (t < NBLK) ? tpart[t] : 0u;
  arr[t] = v;
  __syncthreads();
  for (int off = 1; off < 512; off <<= 1) {
    unsigned u2 = (t >= off) ? arr[t - off] : 0u;
    __syncthreads();
    arr[t] += u2;
    __syncthreads();
  }
  unsigned excl = arr[t] - v;
  if (t < NBLK) tpart[t] = excl;
  unsigned nm = arr[511];
  __syncthreads();
  if (t == 0) {
    unsigned run = 0;
    for (int b = 0; b < NBN; ++b) { unsigned tmp = apart[b]; apart[b] = run; run += tmp; }
    scal[0] = (int)nm;            // n_matched
    scal[2] = (int)run;           // n singleton
    scal[1] = (int)(nm + run);    // num_clusters
  }
}

// ---------- K19: merged finalize (matched clusters + singletons) ----------
__global__ void k_finalize(const unsigned char* __restrict__ take, const int* __restrict__ pay,
                           const int* __restrict__ ss, const int* __restrict__ dd,
                           const float* __restrict__ e, const unsigned* __restrict__ tpart,
                           const int* __restrict__ g_avail, const unsigned* __restrict__ apart,
                           const int* __restrict__ scal, int* __restrict__ cluster,
                           int* __restrict__ clu, int* __restrict__ clv,
                           float* __restrict__ csc) {
  __shared__ unsigned arr[256];
  int t = threadIdx.x; int b = blockIdx.x;
  if (b < NBLK) {
    int base = b * BE + t * 4;
    unsigned char tk[4];
    unsigned c = 0;
    for (int j = 0; j < 4; ++j) {
      int p = base + j;
      tk[j] = (p < N_EDGES) ? take[p] : (unsigned char)0;
      c += tk[j];
    }
    arr[t] = c;
    __syncthreads();
    unsigned v = c;
    for (int off = 1; off < 256; off <<= 1) {
      unsigned u2 = (t >= off) ? arr[t - off] : 0u;
      __syncthreads();
      arr[t] += u2;
      __syncthreads();
    }
    unsigned id = tpart[b] + (arr[t] - v);
    for (int j = 0; j < 4; ++j) {
      int p = base + j;
      if (p < N_EDGES && tk[j]) {
        int s = ss[p], d = dd[p];
        int u = min(s, d), w = max(s, d);
        cluster[s] = (int)id; cluster[d] = (int)id;
        clu[id] = u; clv[id] = w;
        csc[id] = e[pay[p]];
        ++id;
      }
    }
  } else {
    int bb = b - NBLK;
    int base = bb * BE + t * 4;
    unsigned char av[4];
    unsigned c = 0;
    for (int j = 0; j < 4; ++j) {
      int n = base + j;
      av[j] = (n < N_NODES) ? (unsigned char)g_avail[n] : (unsigned char)0;
      c += av[j];
    }
    arr[t] = c;
    __syncthreads();
    unsigned v = c;
    for (int off = 1; off < 256; off <<= 1) {
      unsigned u2 = (t >= off) ? arr[t - off] : 0u;
      __syncthreads();
      arr[t] += u2;
      __syncthreads();
    }
    unsigned id = (unsigned)scal[0] + apart[bb] + (arr[t] - v);
    for (int j = 0; j < 4; ++j) {
      int n = base + j;
      if (n < N_NODES && av[j]) {
        cluster[n] = (int)id;
        clu[id] = n; clv[id] = n;
        csc[id] = 1.0f;
        ++id;
      }
    }
  }
}

// ---------- outputs ----------
__global__ void k_out_x(const float* __restrict__ x, const int* __restrict__ clu,
                        const int* __restrict__ clv, const float* __restrict__ csc,
                        const int* __restrict__ scal, float* __restrict__ out) {
  int c = blockIdx.x; int t = threadIdx.x;
  int nc = scal[1];
  float v = 0.f;
  if (c < nc) {
    int u = clu[c], w = clv[c];
    float a = x[(size_t)u * CDIM + t];
    if (w != u) a = __fadd_rn(a, x[(size_t)w * CDIM + t]);
    v = __fmul_rn(a, csc[c]);
  }
  out[OFF_X + (size_t)c * CDIM + t] = v;
}

// merged: new_edge_index + cluster + new_batch + num_clusters
__global__ void k_out_er(const int* __restrict__ ei, const int* __restrict__ cluster,
                         const int* __restrict__ clv, const int* __restrict__ batch,
                         const int* __restrict__ scal, float* __restrict__ out) {
  int i = blockIdx.x * blockDim.x + threadIdx.x;
  if (i < 2 * N_EDGES) out[OFF_EI + i] = (float)cluster[ei[i]];
  if (i < N_NODES) {
    int nc = scal[1];
    out[OFF_CL + i] = (float)cluster[i];
    out[OFF_B + i] = (i < nc) ? (float)batch[clv[i]] : 0.0f;
    if (i == 0) out[OFF_NC] = (float)nc;
  }
}

extern "C" void kernel_launch(void* const* d_in, const int* in_sizes, int n_in,
                              void* d_out, int out_size, void* d_ws, size_t ws_size,
                              hipStream_t stream) {
  const float* x     = (const float*)d_in[0];
  const int*   ei    = (const int*)d_in[1];
  const int*   batch = (const int*)d_in[2];
  const float* lw    = (const float*)d_in[3];
  const float* lb    = (const float*)d_in[4];
  float* out = (float*)d_out;

  int* w = (int*)d_ws;
  size_t off = 0;
  auto alloc = [&](size_t n) { int* p = w + off; off += n; return p; };
  float*    p1    = (float*)alloc(N_NODES);
  float*    p2    = (float*)alloc(N_NODES);
  float*    e     = (float*)alloc(N_EDGES);
  unsigned* keyA  = (unsigned*)alloc(N_EDGES);
  unsigned* keyB  = (unsigned*)alloc(N_EDGES);
  int*      payA  = (int*)alloc(N_EDGES);
  int*      payB  = (int*)alloc(N_EDGES);
  int*      ss    = (int*)alloc(N_EDGES);
  int*      dd    = (int*)alloc(N_EDGES);
  unsigned* hist  = (unsigned*)alloc(256 * NBLK);
  off = (off + 1) & ~(size_t)1;   // align to 8B for uint64 worklist
  unsigned long long* wl = (unsigned long long*)alloc(2 * N_EDGES);
  unsigned char* take = (unsigned char*)alloc(N_EDGES / 4);
  int*      cluster = (int*)alloc(N_NODES);
  int*      clu   = (int*)alloc(N_NODES);
  int*      clv   = (int*)alloc(N_NODES);
  float*    csc   = (float*)alloc(N_NODES);
  int*      g_avail = (int*)alloc(N_NODES);
  unsigned* tpart = (unsigned*)alloc(NBLK + 1);
  unsigned* apart = (unsigned*)alloc(NBN + 1);
  int*      scal  = (int*)alloc(16);

  // scores + pass-0 histogram (fused)
  k_node_dots<<<(N_NODES + 255) / 256, 256, 0, stream>>>(x, lw, p1, p2);
  k_edge_scores_hist<<<NBLK, 256, 0, stream>>>(ei, p1, p2, lb, e, keyA, payA, hist);

  // stable LSD radix sort, 4 passes: A->B->A->B->(final fused)
  k_radix_scan<<<1, 256, 0, stream>>>(hist);
  k_radix_scatter<<<NBLK, 256, 0, stream>>>(keyA, payA, N_EDGES, 0, hist, keyB, payB);
  k_radix_hist<<<NBLK, 256, 0, stream>>>(keyB, N_EDGES, 8, hist);
  k_radix_scan<<<1, 256, 0, stream>>>(hist);
  k_radix_scatter<<<NBLK, 256, 0, stream>>>(keyB, payB, N_EDGES, 8, hist, keyA, payA);
  k_radix_hist<<<NBLK, 256, 0, stream>>>(keyA, N_EDGES, 16, hist);
  k_radix_scan<<<1, 256, 0, stream>>>(hist);
  k_radix_scatter<<<NBLK, 256, 0, stream>>>(keyA, payA, N_EDGES, 16, hist, keyB, payB);
  k_radix_hist<<<NBLK, 256, 0, stream>>>(keyB, N_EDGES, 24, hist);
  k_radix_scan<<<1, 256, 0, stream>>>(hist);
  k_radix_scatter_final<<<NBLK, 256, 0, stream>>>(keyB, payB, N_EDGES, 24, hist, ei,
                                                  payA, ss, dd, wl, take);

  k_match<<<1, 1024, 0, stream>>>(wl, take, g_avail);

  k_parts<<<NBLK + NBN, 256, 0, stream>>>(take, g_avail, tpart, apart);
  k_scan_parts<<<1, 512, 0, stream>>>(tpart, apart, scal);
  k_finalize<<<NBLK + NBN, 256, 0, stream>>>(take, payA, ss, dd, e, tpart,
                                             g_avail, apart, scal, cluster, clu, clv, csc);

  k_out_x<<<N_NODES, CDIM, 0, stream>>>(x, clu, clv, csc, scal, out);
  k_out_er<<<(2 * N_EDGES + 255) / 256, 256, 0, stream>>>(ei, cluster, clv, batch, scal, out);
}